// Round 8
// baseline (376.951 us; speedup 1.0000x reference)
//
#include <hip/hip_runtime.h>
#include <math.h>
#include <stdint.h>

// ============================ CSR build ============================

__global__ void count_kernel(const int* __restrict__ dst, int* __restrict__ deg, int E) {
  int i = blockIdx.x * 256 + threadIdx.x;
  if (i < E) atomicAdd(&deg[dst[i]], 1);
}

// exclusive scan of (deg[i]+1) (+1 = self loop); single block, single chunk,
// 20 vals/thread fully unrolled (fixed indices -> registers, no scratch).
__global__ void scan_kernel(const int* __restrict__ deg, int* __restrict__ rowptr, int n) {
  __shared__ int buf[1024];
  const int tid = threadIdx.x;
  const int i0 = tid * 20;
  int v[20];
  int tsum = 0;
#pragma unroll
  for (int k = 0; k < 20; ++k) {
    int i = i0 + k;
    v[k] = (i < n) ? (deg[i] + 1) : 0;
    tsum += v[k];
  }
  int incl = tsum;
  buf[tid] = incl;
  __syncthreads();
  for (int s = 1; s < 1024; s <<= 1) {
    int t = (tid >= (unsigned)s) ? buf[tid - s] : 0;
    __syncthreads();
    incl += t;
    buf[tid] = incl;
    __syncthreads();
  }
  int excl = incl - tsum;
#pragma unroll
  for (int k = 0; k < 20; ++k) {
    int i = i0 + k;
    if (i < n) rowptr[i] = excl;
    excl += v[k];
  }
  if (tid == 1023) rowptr[n] = incl;
}

__global__ void scatter_kernel(const int* __restrict__ src, const int* __restrict__ dst,
                               const int* __restrict__ rowptr, int* __restrict__ wp,
                               int* __restrict__ col, int E, int n) {
  int i = blockIdx.x * 256 + threadIdx.x;
  if (i < E) {
    int d = dst[i];
    int p = rowptr[d] + atomicAdd(&wp[d], 1);
    col[p] = src[i];
  } else if (i < E + n) {
    int d = i - E;
    int p = rowptr[d] + atomicAdd(&wp[d], 1);
    col[p] = d;
  }
}

// ==================== bf16 hi/lo split helpers ====================

__device__ __forceinline__ uint16_t bf16r(float x) {
  uint32_t u = __float_as_uint(x);
  return (uint16_t)((u + 0x7FFFu + ((u >> 16) & 1u)) >> 16);
}
__device__ __forceinline__ void bfsplit(float x, uint16_t& h, uint16_t& l) {
  h = bf16r(x);
  float hf = __uint_as_float((uint32_t)h << 16);
  l = bf16r(x - hf);
}

// async 16B global -> LDS (DMA, no VGPR round-trip). LDS dest base is
// wave-uniform; HW adds lane*16. Global src is per-lane.
__device__ __forceinline__ void gload16(const uint16_t* g, uint16_t* l) {
  __builtin_amdgcn_global_load_lds(
      (const __attribute__((address_space(1))) uint32_t*)g,
      (__attribute__((address_space(3))) uint32_t*)l, 16, 0, 0);
}

using bf16x8 = __attribute__((ext_vector_type(8))) short;  // 8 bf16 (4 VGPRs)
using f32x4  = __attribute__((ext_vector_type(4))) float;  // MFMA accumulator

// ==================== MFMA split-bf16 GEMM (async-DMA staged) ====================
// Used only for the LSTM gates GEMM now. C = A @ B, fp32-precision via hi/lo
// bf16 split: C = Ah*Bh + Al*Bh + Ah*Bl. Verified rounds 3-6.

template <bool SPLIT_OUT>
__global__ __launch_bounds__(256) void gemm_mfma(
    const uint16_t* __restrict__ Ah, const uint16_t* __restrict__ Al,
    const uint16_t* __restrict__ Bh, const uint16_t* __restrict__ Bl,
    float* __restrict__ C, uint16_t* __restrict__ Ch, uint16_t* __restrict__ Cl,
    const float* __restrict__ bias,
    int M, int K, int lda, int aZ, int bZ, int ldc, int cZ, int biasZ) {
  constexpr int BM = 64, BN = 64, BK = 64;
  constexpr int PL = BM * BK;  // elements per plane per buffer
  __shared__ __align__(16) uint16_t sAh[2 * PL], sAl[2 * PL];
  __shared__ __align__(16) uint16_t sBh[2 * PL], sBl[2 * PL];
  const int z = blockIdx.z;
  Ah += (size_t)z * aZ; Al += (size_t)z * aZ;
  Bh += (size_t)z * bZ; Bl += (size_t)z * bZ;
  const int tid = threadIdx.x;
  const int wid = tid >> 6, lane = tid & 63;
  // ---- bijective XCD swizzle over (x,y) ----
  int L = blockIdx.x + gridDim.x * blockIdx.y;
  int nwg = gridDim.x * gridDim.y;
  int q = nwg >> 3, r = nwg & 7;
  int xcd = L & 7, gix = L >> 3;
  int base = (xcd < r) ? xcd * (q + 1) : r * (q + 1) + (xcd - r) * q;
  int w = base + gix;
  const int bm = (w / gridDim.x) * BM;
  const int bn = (w % gridDim.x) * BN;
  const int fr = lane & 15;   // row-in-frag (A) / col-in-frag (B,C)
  const int kg = lane >> 4;   // k-group (8 consecutive k each)
  const int mbase = wid * 16;
  f32x4 acc[4] = {};

  auto stage = [&](int sb, int k0) {
#pragma unroll
    for (int j = 0; j < 2; ++j) {
      int idx = (wid * 2 + j) * 64 + lane;
      int row = idx >> 3, c = idx & 7;
      int rg = min(bm + row, M - 1);
      size_t goA = (size_t)rg * lda + k0 + ((c ^ (row & 7)) << 3);
      gload16(Ah + goA, sAh + sb * PL + (wid * 2 + j) * 512);
      gload16(Al + goA, sAl + sb * PL + (wid * 2 + j) * 512);
      size_t goB = (size_t)(bn + row) * K + k0 + ((c ^ (row & 7)) << 3);
      gload16(Bh + goB, sBh + sb * PL + (wid * 2 + j) * 512);
      gload16(Bl + goB, sBl + sb * PL + (wid * 2 + j) * 512);
    }
  };

  stage(0, 0);
  __syncthreads();  // drains vmcnt: tile 0 resident
  int buf = 0;
  for (int k0 = 0; k0 < K; k0 += BK) {
    const bool more = (k0 + BK) < K;
    if (more) stage(buf ^ 1, k0 + BK);  // async; flies during MFMA phase
    const char* pAh = (const char*)sAh + buf * (PL * 2);
    const char* pAl = (const char*)sAl + buf * (PL * 2);
    const char* pBh = (const char*)sBh + buf * (PL * 2);
    const char* pBl = (const char*)sBl + buf * (PL * 2);
#pragma unroll
    for (int ks = 0; ks < 2; ++ks) {
      const int kc = ks * 4 + kg;
      bf16x8 ah, al, bh[4], bl[4];
      {
        int m = mbase + fr;
        int off = m * 128 + ((kc ^ (m & 7)) << 4);
        ah = *reinterpret_cast<const bf16x8*>(pAh + off);
        al = *reinterpret_cast<const bf16x8*>(pAl + off);
      }
#pragma unroll
      for (int j = 0; j < 4; ++j) {
        int n = j * 16 + fr;
        int off = n * 128 + ((kc ^ (n & 7)) << 4);
        bh[j] = *reinterpret_cast<const bf16x8*>(pBh + off);
        bl[j] = *reinterpret_cast<const bf16x8*>(pBl + off);
      }
#pragma unroll
      for (int j = 0; j < 4; ++j) {
        acc[j] = __builtin_amdgcn_mfma_f32_16x16x32_bf16(ah, bh[j], acc[j], 0, 0, 0);
        acc[j] = __builtin_amdgcn_mfma_f32_16x16x32_bf16(al, bh[j], acc[j], 0, 0, 0);
        acc[j] = __builtin_amdgcn_mfma_f32_16x16x32_bf16(ah, bl[j], acc[j], 0, 0, 0);
      }
    }
    if (more) {
      __syncthreads();  // drains prefetch vmcnt + releases buf
      buf ^= 1;
    }
  }
  float bz[4];
#pragma unroll
  for (int j = 0; j < 4; ++j)
    bz[j] = bias ? bias[(size_t)z * biasZ + bn + j * 16 + fr] : 0.f;
  if (SPLIT_OUT) {
    Ch += (size_t)z * cZ;
    Cl += (size_t)z * cZ;
  } else {
    C += (size_t)z * cZ;
  }
  {
    int mr = bm + mbase + kg * 4;
#pragma unroll
    for (int rr = 0; rr < 4; ++rr) {
      int m = mr + rr;
      if (m < M) {
#pragma unroll
        for (int j = 0; j < 4; ++j) {
          float v = acc[j][rr] + bz[j];
          size_t o = (size_t)m * ldc + bn + j * 16 + fr;
          if (SPLIT_OUT) {
            uint16_t h, l;
            bfsplit(v, h, l);
            Ch[o] = h; Cl[o] = l;
          } else {
            C[o] = v;
          }
        }
      }
    }
  }
}

// ==================== merged prep (one launch, also zeroes deg/wp) ====================

__global__ void prep_all_kernel(const float* __restrict__ W_ih, const float* __restrict__ b_ih,
                                const float* __restrict__ b_hh, const float* __restrict__ W1,
                                const float* __restrict__ as1, const float* __restrict__ ad1,
                                const float* __restrict__ W2, const float* __restrict__ as2,
                                const float* __restrict__ ad2,
                                int* __restrict__ degwp,
                                uint16_t* __restrict__ Wtbh, uint16_t* __restrict__ Wtbl,
                                uint16_t* __restrict__ Bt1h, uint16_t* __restrict__ Bt1l,
                                uint16_t* __restrict__ Bt2h, uint16_t* __restrict__ Bt2l,
                                float* __restrict__ bsum, float* __restrict__ watt1,
                                float* __restrict__ watt2, int n2) {
  int idx = blockIdx.x * 256 + threadIdx.x;
  if (idx < n2) {
    degwp[idx] = 0;
    return;
  }
  int t = idx - n2;
  if (t < 98304) {  // Wtb: t = jp*512 + k
    int jp = t >> 9, k = t & 511;
    int j = (jp < 64) ? jp : jp + 64;
    uint16_t h, l;
    bfsplit(W_ih[(size_t)j * 512 + k], h, l);
    Wtbh[t] = h; Wtbl[t] = l;
    return;
  }
  t -= 98304;
  if (t < 65536) {  // Bt1: t = n*128 + k
    int n = t >> 7, k = t & 127;
    uint16_t h, l;
    bfsplit(W1[(size_t)k * 512 + n], h, l);
    Bt1h[t] = h; Bt1l[t] = l;
    return;
  }
  t -= 65536;
  if (t < 32768) {  // Bt2: t = n*64 + k
    int n = t >> 6, k = t & 63;
    uint16_t h, l;
    bfsplit(W2[(size_t)k * 512 + n], h, l);
    Bt2h[t] = h; Bt2l[t] = l;
    return;
  }
  t -= 32768;
  if (t < 192) {
    int j = (t < 64) ? t : t + 64;
    bsum[t] = b_ih[j] + b_hh[j];
    return;
  }
  t -= 192;
  if (t < 2048) {
    int f = t >> 4, c = t & 15;
    int k = c & 7;
    const float* att = ((c < 8) ? as1 : ad1) + k * 64;
    const float* w = W1 + (size_t)f * 512 + k * 64;
    float s = 0.f;
#pragma unroll
    for (int j = 0; j < 64; ++j) s = fmaf(w[j], att[j], s);
    watt1[t] = s;
    return;
  }
  t -= 2048;
  if (t < 1024) {
    int f = t >> 4, c = t & 15;
    int k = c & 7;
    const float* att = ((c < 8) ? as2 : ad2) + k * 64;
    const float* w = W2 + (size_t)f * 512 + k * 64;
    float s = 0.f;
#pragma unroll
    for (int j = 0; j < 64; ++j) s = fmaf(w[j], att[j], s);
    watt2[t] = s;
  }
}

// ==================== attention coefficients (layer 1) ====================

template <int F>
__global__ __launch_bounds__(256) void attcoef_kernel(
    const float* __restrict__ feat, const float* __restrict__ watt,
    float* __restrict__ a_s, float* __restrict__ a_d, int n) {
  __shared__ float rows[16 * F];
  __shared__ float wbuf[F * 16];
  const int n0 = blockIdx.x * 16;
  const int tid = threadIdx.x;
  if (n0 + 16 <= n) {
    const float4* g = reinterpret_cast<const float4*>(feat + (size_t)n0 * F);
    float4* l = reinterpret_cast<float4*>(rows);
    for (int i = tid; i < 16 * F / 4; i += 256) l[i] = g[i];
  } else {
    for (int i = tid; i < 16 * F; i += 256) {
      int r = i / F;
      rows[i] = (n0 + r < n) ? feat[(size_t)(n0 + r) * F + (i - r * F)] : 0.f;
    }
  }
  {
    const float4* g = reinterpret_cast<const float4*>(watt);
    float4* l = reinterpret_cast<float4*>(wbuf);
    for (int i = tid; i < F * 16 / 4; i += 256) l[i] = g[i];
  }
  __syncthreads();
  const int local = tid >> 4, c = tid & 15;
  float s = 0.f;
#pragma unroll 8
  for (int f = 0; f < F; ++f) s = fmaf(rows[local * F + f], wbuf[f * 16 + c], s);
  const int node = n0 + local;
  if (node < n) {
    if (c < 8) a_s[(size_t)node * 8 + c] = s;
    else       a_d[(size_t)node * 8 + (c - 8)] = s;
  }
}

// ==================== FUSED GAT: aggregate (VALU) + project (MFMA) ====================
// Kills the agg intermediate (80 MB write + 80 MB re-read for layer 1).
// Block = 512 threads (8 waves), 16 nodes.
// Phase 1: wave w aggregates nodes w*2, w*2+1 (round-6 verified inner loop;
//   s_ex/s_cols replaced by uniform __shfl broadcasts - no LDS, no barriers),
//   deferred-normalizes, stores hi/lo bf16 A-tile to LDS with the GEMM's
//   XOR swizzle (byte ^= (row&7)<<4 at 16B granularity).
// Phase 2 (one __syncthreads): wave w projects head w: M=16 nodes, N=64,
//   K=F via mfma_16x16x32_bf16 hi/lo triple (same verified fragment map as
//   gemm_mfma). B = W planes [head*64+n][k], streamed from global (L2-hot,
//   256KB). Epilogue: bias + fp32 store (or hi/lo split for the LSTM input).
// Barrier safety: no early returns; all threads reach the __syncthreads.
// All __shfl ops execute on all 64 lanes (uniform loop bounds).

template <int F, bool SPLIT_OUT>
__global__ __launch_bounds__(512) void gat_fused(
    const float* __restrict__ feat, const float* __restrict__ a_s,
    const float* __restrict__ a_d, const int* __restrict__ rowptr,
    const int* __restrict__ col,
    const uint16_t* __restrict__ Bh, const uint16_t* __restrict__ Bl,
    const float* __restrict__ bias, float* __restrict__ C,
    uint16_t* __restrict__ Ch, uint16_t* __restrict__ Cl, int n) {
  constexpr int FL = F / 4;      // float4 slots per feature row
  constexpr int HPW = FL / 8;    // heads per lane (4 for F=128, 2 for F=64)
  __shared__ uint16_t AtH[8][16][F];  // [head][node-row][k], swizzled
  __shared__ uint16_t AtL[8][16][F];
  const int tid = threadIdx.x;
  const int wid = tid >> 6, lane = tid & 63;
  const int nb0 = blockIdx.x * 16;
  const int j = lane >> 3, h = lane & 7;      // phase-1 exp roles
  const int grp = lane / FL, f4 = lane & (FL - 1);
  const int hbase = grp * HPW;

  // ---------------- phase 1: aggregate 2 nodes per wave ----------------
  for (int i = 0; i < 2; ++i) {
    const int r = wid * 2 + i;     // block-local A-row 0..15
    const int node = nb0 + r;
    int start = 0, deg = 0;
    float adh = 0.f;
    if (node < n) {
      start = rowptr[node];
      deg = rowptr[node + 1] - start;
      adh = a_d[(size_t)node * 8 + h];
    }
    float dpart = 0.f;
    float4 acc[HPW];
#pragma unroll
    for (int q = 0; q < HPW; ++q) acc[q] = make_float4(0.f, 0.f, 0.f, 0.f);

    for (int c0 = 0; c0 < deg; c0 += 8) {
      float ex = 0.f;
      int sj = 0;
      if (c0 + j < deg) {
        sj = col[start + c0 + j];
        float v = a_s[(size_t)sj * 8 + h] + adh;
        v = (v > 0.f) ? v : 0.2f * v;
        ex = __expf(v);
      }
      dpart += ex;
      if (deg - c0 >= 8) {
        // fast path: 8 gathers in flight, then FMAs
        int se[8];
        float4 fv[8];
#pragma unroll
        for (int e = 0; e < 8; ++e) se[e] = __shfl(sj, e * 8);
#pragma unroll
        for (int e = 0; e < 8; ++e)
          fv[e] = *reinterpret_cast<const float4*>(feat + (size_t)se[e] * F + f4 * 4);
#pragma unroll
        for (int e = 0; e < 8; ++e) {
          float alv[HPW];
#pragma unroll
          for (int q = 0; q < HPW; ++q) alv[q] = __shfl(ex, e * 8 + hbase + q);
#pragma unroll
          for (int q = 0; q < HPW; ++q) {
            acc[q].x = fmaf(alv[q], fv[e].x, acc[q].x);
            acc[q].y = fmaf(alv[q], fv[e].y, acc[q].y);
            acc[q].z = fmaf(alv[q], fv[e].z, acc[q].z);
            acc[q].w = fmaf(alv[q], fv[e].w, acc[q].w);
          }
        }
      } else {
        const int ce = deg - c0;
        for (int e = 0; e < ce; ++e) {   // ce is wave-uniform
          int s = __shfl(sj, e * 8);
          float4 fv = *reinterpret_cast<const float4*>(feat + (size_t)s * F + f4 * 4);
          float alv[HPW];
#pragma unroll
          for (int q = 0; q < HPW; ++q) alv[q] = __shfl(ex, e * 8 + hbase + q);
#pragma unroll
          for (int q = 0; q < HPW; ++q) {
            acc[q].x = fmaf(alv[q], fv.x, acc[q].x);
            acc[q].y = fmaf(alv[q], fv.y, acc[q].y);
            acc[q].z = fmaf(alv[q], fv.z, acc[q].z);
            acc[q].w = fmaf(alv[q], fv.w, acc[q].w);
          }
        }
      }
    }
    // denominator reduce over edge-slots (lane bits 3..5)
    dpart += __shfl_xor(dpart, 8);
    dpart += __shfl_xor(dpart, 16);
    dpart += __shfl_xor(dpart, 32);
    // normalize + split-store A-rows to LDS (swizzled). All shfl uniform.
    const int swz = (f4 * 8) ^ ((r & 7) << 4);
#pragma unroll
    for (int q = 0; q < HPW; ++q) {
      float dq = __shfl(dpart, hbase + q);
      float dinv = 1.f / (dq + 1e-16f);
      ushort4 hi4, lo4;
      bfsplit(acc[q].x * dinv, hi4.x, lo4.x);
      bfsplit(acc[q].y * dinv, hi4.y, lo4.y);
      bfsplit(acc[q].z * dinv, hi4.z, lo4.z);
      bfsplit(acc[q].w * dinv, hi4.w, lo4.w);
      *reinterpret_cast<ushort4*>(
          reinterpret_cast<char*>(&AtH[hbase + q][r][0]) + swz) = hi4;
      *reinterpret_cast<ushort4*>(
          reinterpret_cast<char*>(&AtL[hbase + q][r][0]) + swz) = lo4;
    }
  }
  __syncthreads();

  // ---------------- phase 2: wave wid projects head wid ----------------
  const int hd = wid;
  const int fr = lane & 15, kg = lane >> 4;
  const uint16_t* Bhh = Bh + (size_t)(hd * 64) * F;
  const uint16_t* Blh = Bl + (size_t)(hd * 64) * F;
  f32x4 pacc[4] = {};
#pragma unroll
  for (int ks = 0; ks < F / 32; ++ks) {
    const int kc = ks * 4 + kg;
    const int aoff = (kc * 16) ^ ((fr & 7) << 4);
    bf16x8 ah = *reinterpret_cast<const bf16x8*>(
        reinterpret_cast<const char*>(&AtH[hd][fr][0]) + aoff);
    bf16x8 al = *reinterpret_cast<const bf16x8*>(
        reinterpret_cast<const char*>(&AtL[hd][fr][0]) + aoff);
#pragma unroll
    for (int jf = 0; jf < 4; ++jf) {
      const size_t bro = (size_t)(jf * 16 + fr) * F + kc * 8;
      bf16x8 bh = *reinterpret_cast<const bf16x8*>(Bhh + bro);
      bf16x8 bl = *reinterpret_cast<const bf16x8*>(Blh + bro);
      pacc[jf] = __builtin_amdgcn_mfma_f32_16x16x32_bf16(ah, bh, pacc[jf], 0, 0, 0);
      pacc[jf] = __builtin_amdgcn_mfma_f32_16x16x32_bf16(al, bh, pacc[jf], 0, 0, 0);
      pacc[jf] = __builtin_amdgcn_mfma_f32_16x16x32_bf16(ah, bl, pacc[jf], 0, 0, 0);
    }
  }
  // epilogue: C/D layout col = lane&15, row = (lane>>4)*4 + rr
#pragma unroll
  for (int jf = 0; jf < 4; ++jf) {
    const int colg = hd * 64 + jf * 16 + fr;
    const float bz = bias[colg];
#pragma unroll
    for (int rr = 0; rr < 4; ++rr) {
      int m = nb0 + kg * 4 + rr;
      if (m < n) {
        float v = pacc[jf][rr] + bz;
        size_t o = (size_t)m * 512 + colg;
        if (SPLIT_OUT) {
          uint16_t hh2, ll2;
          bfsplit(v, hh2, ll2);
          Ch[o] = hh2; Cl[o] = ll2;
        } else {
          C[o] = v;
        }
      }
    }
  }
}

// ==================== fused LSTM activation + attcoef2 ====================

__global__ __launch_bounds__(256) void lstm_act_attcoef_kernel(
    const float* __restrict__ gates, const float* __restrict__ bsum,
    const float* __restrict__ watt2, float* __restrict__ h2,
    float* __restrict__ a_s2, float* __restrict__ a_d2, int n) {
  __shared__ float h2t[4][64];
  __shared__ float wbuf[64 * 16];
  const int tid = threadIdx.x;
  reinterpret_cast<float4*>(wbuf)[tid] = reinterpret_cast<const float4*>(watt2)[tid];
  const int nl = tid >> 6, j = tid & 63;
  const int node = blockIdx.x * 4 + nl;
  float hv = 0.f;
  if (node < n) {
    const float* g0 = gates + (size_t)node * 192;
    float iv = g0[j] + bsum[j];
    float gv = g0[64 + j] + bsum[64 + j];
    float ov = g0[128 + j] + bsum[128 + j];
    float c = (1.f / (1.f + __expf(-iv))) * tanhf(gv);
    hv = fmaxf((1.f / (1.f + __expf(-ov))) * tanhf(c), 0.f);
    h2[(size_t)node * 64 + j] = hv;
  }
  h2t[nl][j] = hv;
  __syncthreads();
  if (j < 16 && node < n) {
    float s = 0.f;
#pragma unroll 16
    for (int f = 0; f < 64; ++f) s = fmaf(h2t[nl][f], wbuf[f * 16 + j], s);
    if (j < 8) a_s2[(size_t)node * 8 + j] = s;
    else       a_d2[(size_t)node * 8 + (j - 8)] = s;
  }
}

// ==================== final row softmax: one WAVE per node ====================

__global__ __launch_bounds__(256) void softmax512_wave(const float* __restrict__ in,
                                                       float* __restrict__ out, int n) {
  const int wid = threadIdx.x >> 6, lane = threadIdx.x & 63;
  const int node = blockIdx.x * 4 + wid;
  if (node >= n) return;
  const float4* ip = reinterpret_cast<const float4*>(in + (size_t)node * 512);
  float4 v0 = ip[lane];
  float4 v1 = ip[64 + lane];
  float m = fmaxf(fmaxf(fmaxf(v0.x, v0.y), fmaxf(v0.z, v0.w)),
                  fmaxf(fmaxf(v1.x, v1.y), fmaxf(v1.z, v1.w)));
#pragma unroll
  for (int d = 1; d < 64; d <<= 1) m = fmaxf(m, __shfl_xor(m, d));
  float4 e0, e1;
  e0.x = __expf(v0.x - m); e0.y = __expf(v0.y - m);
  e0.z = __expf(v0.z - m); e0.w = __expf(v0.w - m);
  e1.x = __expf(v1.x - m); e1.y = __expf(v1.y - m);
  e1.z = __expf(v1.z - m); e1.w = __expf(v1.w - m);
  float s = e0.x + e0.y + e0.z + e0.w + e1.x + e1.y + e1.z + e1.w;
#pragma unroll
  for (int d = 1; d < 64; d <<= 1) s += __shfl_xor(s, d);
  float inv = 1.f / s;
  e0.x *= inv; e0.y *= inv; e0.z *= inv; e0.w *= inv;
  e1.x *= inv; e1.y *= inv; e1.z *= inv; e1.w *= inv;
  float4* op = reinterpret_cast<float4*>(out + (size_t)node * 512);
  op[lane] = e0;
  op[64 + lane] = e1;
}

// ============================ launch ============================

extern "C" void kernel_launch(void* const* d_in, const int* in_sizes, int n_in,
                              void* d_out, int out_size, void* d_ws, size_t ws_size,
                              hipStream_t stream) {
  const float* x      = (const float*)d_in[0];
  const int*   ei     = (const int*)d_in[1];
  const float* W1     = (const float*)d_in[3];
  const float* att_s1 = (const float*)d_in[4];
  const float* att_d1 = (const float*)d_in[5];
  const float* bias1  = (const float*)d_in[6];
  const float* W_ih   = (const float*)d_in[7];
  const float* b_ih   = (const float*)d_in[9];
  const float* b_hh   = (const float*)d_in[10];
  const float* W2     = (const float*)d_in[11];
  const float* att_s2 = (const float*)d_in[12];
  const float* att_d2 = (const float*)d_in[13];
  const float* bias2  = (const float*)d_in[14];
  float* out = (float*)d_out;

  const int N = in_sizes[0] / 128;
  const int E = in_sizes[1] / 2;
  const int* src = ei;
  const int* dst = ei + E;

  char* p = (char*)d_ws;
  auto alloc = [&](size_t bytes) {
    char* r = p;
    p += (bytes + 255) & ~(size_t)255;
    return r;
  };
  char* slotA = alloc((size_t)N * 4096);  // gates2 + h2
  char* slotB = alloc((size_t)N * 2048);  // g1 planes; later h3p
  float* a_s1 = (float*)alloc((size_t)N * 8 * 4);
  float* a_d1 = (float*)alloc((size_t)N * 8 * 4);
  float* a_s2 = (float*)alloc((size_t)N * 8 * 4);
  float* a_d2 = (float*)alloc((size_t)N * 8 * 4);
  float* watt1 = (float*)alloc(128 * 16 * 4);
  float* watt2 = (float*)alloc(64 * 16 * 4);
  uint16_t* Wtbh = (uint16_t*)alloc((size_t)192 * 512 * 2);
  uint16_t* Wtbl = (uint16_t*)alloc((size_t)192 * 512 * 2);
  uint16_t* Bt1h = (uint16_t*)alloc((size_t)512 * 128 * 2);
  uint16_t* Bt1l = (uint16_t*)alloc((size_t)512 * 128 * 2);
  uint16_t* Bt2h = (uint16_t*)alloc((size_t)512 * 64 * 2);
  uint16_t* Bt2l = (uint16_t*)alloc((size_t)512 * 64 * 2);
  float* bsum = (float*)alloc(192 * 4);
  int* deg    = (int*)alloc((size_t)2 * N * 4);  // deg + wp adjacent
  int* wp     = deg + N;
  int* rowptr = (int*)alloc((size_t)(N + 1) * 4);
  int* col    = (int*)alloc((size_t)(E + N) * 4);

  float* gates2 = (float*)slotA;                    // [N,192]
  float* h2 = (float*)(slotA + (size_t)N * 768);    // [N,64]
  uint16_t* g1h = (uint16_t*)slotB;                 // [N,512] bf16 hi
  uint16_t* g1l = g1h + (size_t)N * 512;            // [N,512] bf16 lo
  float* h3p = (float*)slotB;                       // [N,512] logits (after LSTM gemm)

  // ---- merged prep (also zeroes deg/wp) ----
  {
    int total = 2 * N + 98304 + 65536 + 32768 + 192 + 2048 + 1024;
    prep_all_kernel<<<(total + 255) / 256, 256, 0, stream>>>(
        W_ih, b_ih, b_hh, W1, att_s1, att_d1, W2, att_s2, att_d2,
        deg, Wtbh, Wtbl, Bt1h, Bt1l, Bt2h, Bt2l, bsum, watt1, watt2, 2 * N);
  }

  // ---- CSR build ----
  count_kernel<<<(E + 255) / 256, 256, 0, stream>>>(dst, deg, E);
  scan_kernel<<<1, 1024, 0, stream>>>(deg, rowptr, N);
  scatter_kernel<<<(E + N + 255) / 256, 256, 0, stream>>>(src, dst, rowptr, wp, col, E, N);

  // ---- GATConv1 fused: aggregate x + project -> g1 planes (+bias1) ----
  attcoef_kernel<128><<<(N + 15) / 16, 256, 0, stream>>>(x, watt1, a_s1, a_d1, N);
  gat_fused<128, true><<<(N + 15) / 16, 512, 0, stream>>>(
      x, a_s1, a_d1, rowptr, col, Bt1h, Bt1l, bias1, nullptr, g1h, g1l, N);

  // ---- LSTM gates GEMM + fused act/attcoef2 ----
  {
    dim3 g(3, (N + 63) / 64, 1);
    gemm_mfma<false><<<g, 256, 0, stream>>>(
        g1h, g1l, Wtbh, Wtbl, gates2, nullptr, nullptr, nullptr,
        N, 512, /*lda*/512, 0, 0, /*ldc*/192, 0, 0);
  }
  lstm_act_attcoef_kernel<<<(N + 3) / 4, 256, 0, stream>>>(gates2, bsum, watt2,
                                                           h2, a_s2, a_d2, N);

  // ---- GATConv2 fused: aggregate h2 + project -> h3p (+bias2), softmax ----
  gat_fused<64, false><<<(N + 15) / 16, 512, 0, stream>>>(
      h2, a_s2, a_d2, rowptr, col, Bt2h, Bt2l, bias2, h3p, nullptr, nullptr, N);
  softmax512_wave<<<(N + 3) / 4, 256, 0, stream>>>(h3p, out, N);
}

// Round 9
// 320.629 us; speedup vs baseline: 1.1757x; 1.1757x over previous
//
#include <hip/hip_runtime.h>
#include <math.h>
#include <stdint.h>

// ============================ CSR build ============================

__global__ void count_kernel(const int* __restrict__ dst, int* __restrict__ deg, int E) {
  int i = blockIdx.x * 256 + threadIdx.x;
  if (i < E) atomicAdd(&deg[dst[i]], 1);
}

// exclusive scan of (deg[i]+1) (+1 = self loop); single block, single chunk,
// 20 vals/thread fully unrolled (fixed indices -> registers, no scratch).
__global__ void scan_kernel(const int* __restrict__ deg, int* __restrict__ rowptr, int n) {
  __shared__ int buf[1024];
  const int tid = threadIdx.x;
  const int i0 = tid * 20;
  int v[20];
  int tsum = 0;
#pragma unroll
  for (int k = 0; k < 20; ++k) {
    int i = i0 + k;
    v[k] = (i < n) ? (deg[i] + 1) : 0;
    tsum += v[k];
  }
  int incl = tsum;
  buf[tid] = incl;
  __syncthreads();
  for (int s = 1; s < 1024; s <<= 1) {
    int t = (tid >= (unsigned)s) ? buf[tid - s] : 0;
    __syncthreads();
    incl += t;
    buf[tid] = incl;
    __syncthreads();
  }
  int excl = incl - tsum;
#pragma unroll
  for (int k = 0; k < 20; ++k) {
    int i = i0 + k;
    if (i < n) rowptr[i] = excl;
    excl += v[k];
  }
  if (tid == 1023) rowptr[n] = incl;
}

__global__ void scatter_kernel(const int* __restrict__ src, const int* __restrict__ dst,
                               const int* __restrict__ rowptr, int* __restrict__ wp,
                               int* __restrict__ col, int E, int n) {
  int i = blockIdx.x * 256 + threadIdx.x;
  if (i < E) {
    int d = dst[i];
    int p = rowptr[d] + atomicAdd(&wp[d], 1);
    col[p] = src[i];
  } else if (i < E + n) {
    int d = i - E;
    int p = rowptr[d] + atomicAdd(&wp[d], 1);
    col[p] = d;
  }
}

// ==================== bf16 hi/lo split helpers ====================

__device__ __forceinline__ uint16_t bf16r(float x) {
  uint32_t u = __float_as_uint(x);
  return (uint16_t)((u + 0x7FFFu + ((u >> 16) & 1u)) >> 16);
}
__device__ __forceinline__ void bfsplit(float x, uint16_t& h, uint16_t& l) {
  h = bf16r(x);
  float hf = __uint_as_float((uint32_t)h << 16);
  l = bf16r(x - hf);
}
__device__ __forceinline__ void store4split(uint16_t* oh, uint16_t* ol, float4 v) {
  ushort4 h, l;
  bfsplit(v.x, h.x, l.x); bfsplit(v.y, h.y, l.y);
  bfsplit(v.z, h.z, l.z); bfsplit(v.w, h.w, l.w);
  *reinterpret_cast<ushort4*>(oh) = h;
  *reinterpret_cast<ushort4*>(ol) = l;
}

// async 16B global -> LDS (DMA, no VGPR round-trip). LDS dest base is
// wave-uniform; HW adds lane*16. Global src is per-lane.
__device__ __forceinline__ void gload16(const uint16_t* g, uint16_t* l) {
  __builtin_amdgcn_global_load_lds(
      (const __attribute__((address_space(1))) uint32_t*)g,
      (__attribute__((address_space(3))) uint32_t*)l, 16, 0, 0);
}

using bf16x8 = __attribute__((ext_vector_type(8))) short;  // 8 bf16 (4 VGPRs)
using f32x4  = __attribute__((ext_vector_type(4))) float;  // MFMA accumulator

// ==================== MFMA split-bf16 GEMM (async-DMA staged) ====================
// C = A @ B (+bias), fp32-precision via hi/lo bf16 split:
//   C = Ah*Bh + Al*Bh + Ah*Bl   (Al*Bl ~ 2^-18 dropped)
// A and B are pre-split bf16 planes, [rows][K]. global_load_lds staging
// (LDS dest linear, global src pre-swizzled chunk c^(row&7)); 2-phase
// pipeline. Verified rounds 3-6.

template <bool SPLIT_OUT>
__global__ __launch_bounds__(256) void gemm_mfma(
    const uint16_t* __restrict__ Ah, const uint16_t* __restrict__ Al,
    const uint16_t* __restrict__ Bh, const uint16_t* __restrict__ Bl,
    float* __restrict__ C, uint16_t* __restrict__ Ch, uint16_t* __restrict__ Cl,
    const float* __restrict__ bias,
    int M, int K, int lda, int aZ, int bZ, int ldc, int cZ, int biasZ) {
  constexpr int BM = 64, BN = 64, BK = 64;
  constexpr int PL = BM * BK;  // elements per plane per buffer
  __shared__ __align__(16) uint16_t sAh[2 * PL], sAl[2 * PL];
  __shared__ __align__(16) uint16_t sBh[2 * PL], sBl[2 * PL];
  const int z = blockIdx.z;
  Ah += (size_t)z * aZ; Al += (size_t)z * aZ;
  Bh += (size_t)z * bZ; Bl += (size_t)z * bZ;
  const int tid = threadIdx.x;
  const int wid = tid >> 6, lane = tid & 63;
  // ---- bijective XCD swizzle over (x,y) ----
  int L = blockIdx.x + gridDim.x * blockIdx.y;
  int nwg = gridDim.x * gridDim.y;
  int q = nwg >> 3, r = nwg & 7;
  int xcd = L & 7, gix = L >> 3;
  int base = (xcd < r) ? xcd * (q + 1) : r * (q + 1) + (xcd - r) * q;
  int w = base + gix;
  const int bm = (w / gridDim.x) * BM;
  const int bn = (w % gridDim.x) * BN;
  const int fr = lane & 15;   // row-in-frag (A) / col-in-frag (B,C)
  const int kg = lane >> 4;   // k-group (8 consecutive k each)
  const int mbase = wid * 16;
  f32x4 acc[4] = {};

  auto stage = [&](int sb, int k0) {
#pragma unroll
    for (int j = 0; j < 2; ++j) {
      int idx = (wid * 2 + j) * 64 + lane;
      int row = idx >> 3, c = idx & 7;
      int rg = min(bm + row, M - 1);
      size_t goA = (size_t)rg * lda + k0 + ((c ^ (row & 7)) << 3);
      gload16(Ah + goA, sAh + sb * PL + (wid * 2 + j) * 512);
      gload16(Al + goA, sAl + sb * PL + (wid * 2 + j) * 512);
      size_t goB = (size_t)(bn + row) * K + k0 + ((c ^ (row & 7)) << 3);
      gload16(Bh + goB, sBh + sb * PL + (wid * 2 + j) * 512);
      gload16(Bl + goB, sBl + sb * PL + (wid * 2 + j) * 512);
    }
  };

  stage(0, 0);
  __syncthreads();  // drains vmcnt: tile 0 resident
  int buf = 0;
  for (int k0 = 0; k0 < K; k0 += BK) {
    const bool more = (k0 + BK) < K;
    if (more) stage(buf ^ 1, k0 + BK);  // async; flies during MFMA phase
    const char* pAh = (const char*)sAh + buf * (PL * 2);
    const char* pAl = (const char*)sAl + buf * (PL * 2);
    const char* pBh = (const char*)sBh + buf * (PL * 2);
    const char* pBl = (const char*)sBl + buf * (PL * 2);
#pragma unroll
    for (int ks = 0; ks < 2; ++ks) {
      const int kc = ks * 4 + kg;
      bf16x8 ah, al, bh[4], bl[4];
      {
        int m = mbase + fr;
        int off = m * 128 + ((kc ^ (m & 7)) << 4);
        ah = *reinterpret_cast<const bf16x8*>(pAh + off);
        al = *reinterpret_cast<const bf16x8*>(pAl + off);
      }
#pragma unroll
      for (int j = 0; j < 4; ++j) {
        int n = j * 16 + fr;
        int off = n * 128 + ((kc ^ (n & 7)) << 4);
        bh[j] = *reinterpret_cast<const bf16x8*>(pBh + off);
        bl[j] = *reinterpret_cast<const bf16x8*>(pBl + off);
      }
#pragma unroll
      for (int j = 0; j < 4; ++j) {
        acc[j] = __builtin_amdgcn_mfma_f32_16x16x32_bf16(ah, bh[j], acc[j], 0, 0, 0);
        acc[j] = __builtin_amdgcn_mfma_f32_16x16x32_bf16(al, bh[j], acc[j], 0, 0, 0);
        acc[j] = __builtin_amdgcn_mfma_f32_16x16x32_bf16(ah, bl[j], acc[j], 0, 0, 0);
      }
    }
    if (more) {
      __syncthreads();  // drains prefetch vmcnt + releases buf
      buf ^= 1;
    }
  }
  float bz[4];
#pragma unroll
  for (int j = 0; j < 4; ++j)
    bz[j] = bias ? bias[(size_t)z * biasZ + bn + j * 16 + fr] : 0.f;
  if (SPLIT_OUT) {
    Ch += (size_t)z * cZ;
    Cl += (size_t)z * cZ;
  } else {
    C += (size_t)z * cZ;
  }
  {
    int mr = bm + mbase + kg * 4;
#pragma unroll
    for (int rr = 0; rr < 4; ++rr) {
      int m = mr + rr;
      if (m < M) {
#pragma unroll
        for (int j = 0; j < 4; ++j) {
          float v = acc[j][rr] + bz[j];
          size_t o = (size_t)m * ldc + bn + j * 16 + fr;
          if (SPLIT_OUT) {
            uint16_t h, l;
            bfsplit(v, h, l);
            Ch[o] = h; Cl[o] = l;
          } else {
            C[o] = v;
          }
        }
      }
    }
  }
}

// ==================== merged prep (one launch, also zeroes deg/wp) ====================

__global__ void prep_all_kernel(const float* __restrict__ W_ih, const float* __restrict__ b_ih,
                                const float* __restrict__ b_hh, const float* __restrict__ W1,
                                const float* __restrict__ as1, const float* __restrict__ ad1,
                                const float* __restrict__ W2, const float* __restrict__ as2,
                                const float* __restrict__ ad2,
                                int* __restrict__ degwp,
                                uint16_t* __restrict__ Wtbh, uint16_t* __restrict__ Wtbl,
                                uint16_t* __restrict__ Bt1h, uint16_t* __restrict__ Bt1l,
                                uint16_t* __restrict__ Bt2h, uint16_t* __restrict__ Bt2l,
                                float* __restrict__ bsum, float* __restrict__ watt1,
                                float* __restrict__ watt2, int n2) {
  int idx = blockIdx.x * 256 + threadIdx.x;
  if (idx < n2) {
    degwp[idx] = 0;
    return;
  }
  int t = idx - n2;
  if (t < 98304) {  // Wtb: t = jp*512 + k
    int jp = t >> 9, k = t & 511;
    int j = (jp < 64) ? jp : jp + 64;
    uint16_t h, l;
    bfsplit(W_ih[(size_t)j * 512 + k], h, l);
    Wtbh[t] = h; Wtbl[t] = l;
    return;
  }
  t -= 98304;
  if (t < 65536) {  // Bt1: t = n*128 + k
    int n = t >> 7, k = t & 127;
    uint16_t h, l;
    bfsplit(W1[(size_t)k * 512 + n], h, l);
    Bt1h[t] = h; Bt1l[t] = l;
    return;
  }
  t -= 65536;
  if (t < 32768) {  // Bt2: t = n*64 + k
    int n = t >> 6, k = t & 63;
    uint16_t h, l;
    bfsplit(W2[(size_t)k * 512 + n], h, l);
    Bt2h[t] = h; Bt2l[t] = l;
    return;
  }
  t -= 32768;
  if (t < 192) {
    int j = (t < 64) ? t : t + 64;
    bsum[t] = b_ih[j] + b_hh[j];
    return;
  }
  t -= 192;
  if (t < 2048) {
    int f = t >> 4, c = t & 15;
    int k = c & 7;
    const float* att = ((c < 8) ? as1 : ad1) + k * 64;
    const float* w = W1 + (size_t)f * 512 + k * 64;
    float s = 0.f;
#pragma unroll
    for (int j = 0; j < 64; ++j) s = fmaf(w[j], att[j], s);
    watt1[t] = s;
    return;
  }
  t -= 2048;
  if (t < 1024) {
    int f = t >> 4, c = t & 15;
    int k = c & 7;
    const float* att = ((c < 8) ? as2 : ad2) + k * 64;
    const float* w = W2 + (size_t)f * 512 + k * 64;
    float s = 0.f;
#pragma unroll
    for (int j = 0; j < 64; ++j) s = fmaf(w[j], att[j], s);
    watt2[t] = s;
  }
}

// ==================== attention coefficients (layer 1) ====================

template <int F>
__global__ __launch_bounds__(256) void attcoef_kernel(
    const float* __restrict__ feat, const float* __restrict__ watt,
    float* __restrict__ a_s, float* __restrict__ a_d, int n) {
  __shared__ float rows[16 * F];
  __shared__ float wbuf[F * 16];
  const int n0 = blockIdx.x * 16;
  const int tid = threadIdx.x;
  if (n0 + 16 <= n) {
    const float4* g = reinterpret_cast<const float4*>(feat + (size_t)n0 * F);
    float4* l = reinterpret_cast<float4*>(rows);
    for (int i = tid; i < 16 * F / 4; i += 256) l[i] = g[i];
  } else {
    for (int i = tid; i < 16 * F; i += 256) {
      int r = i / F;
      rows[i] = (n0 + r < n) ? feat[(size_t)(n0 + r) * F + (i - r * F)] : 0.f;
    }
  }
  {
    const float4* g = reinterpret_cast<const float4*>(watt);
    float4* l = reinterpret_cast<float4*>(wbuf);
    for (int i = tid; i < F * 16 / 4; i += 256) l[i] = g[i];
  }
  __syncthreads();
  const int local = tid >> 4, c = tid & 15;
  float s = 0.f;
#pragma unroll 8
  for (int f = 0; f < F; ++f) s = fmaf(rows[local * F + f], wbuf[f * 16 + c], s);
  const int node = n0 + local;
  if (node < n) {
    if (c < 8) a_s[(size_t)node * 8 + c] = s;
    else       a_d[(size_t)node * 8 + (c - 8)] = s;
  }
}

// ==================== GAT pre-aggregation: one WAVE per dst node ====================
// 64-edge STAGING WINDOW (this round's change): Pass A stages raw exp for up
// to 64 edges in one fully-unrolled independent loop (16+ gathers in flight),
// ONE wave fence, then Pass B runs the static-8 feature-gather pipeline
// across the whole window with no intervening fences. Round 6 alternated
// exp-stage/feat-gather per 8-edge chunk -> 6 serial latency rounds per node
// at deg~17; this is 2. Per-lane head ownership, deferred normalization, and
// epilogue are round-6-verified (all __shfl uniform, no divergent sources).

template <int F>
__global__ __launch_bounds__(256) void gat_aggregate_wave(
    const float* __restrict__ feat, const float* __restrict__ a_s,
    const float* __restrict__ a_d, const int* __restrict__ rowptr,
    const int* __restrict__ col, uint16_t* __restrict__ aggH,
    uint16_t* __restrict__ aggL, int n) {
  constexpr int FL = F / 4;                // float4 slots per row
  constexpr int HPW = (F == 128) ? 4 : 2;  // heads owned per lane
  __shared__ float s_ex[4][64][8];
  __shared__ int s_cols[4][64];
  const int wid = threadIdx.x >> 6;
  const int lane = threadIdx.x & 63;
  const int node = blockIdx.x * 4 + wid;
  if (node >= n) return;  // only wave-level fences below: safe
  const int start = rowptr[node];
  const int deg = rowptr[node + 1] - start;
  const int j = lane >> 3;             // staging role: edge slot
  const int h = lane & 7;              // staging role: head
  const int f4 = lane & (FL - 1);      // fma role: float4 index
  const int hbase = (lane / FL) * HPW; // fma role: first owned head
  const float adh = a_d[(size_t)node * 8 + h];
  float dpart = 0.f;
  float4 acc[HPW];
#pragma unroll
  for (int q = 0; q < HPW; ++q) acc[q] = make_float4(0.f, 0.f, 0.f, 0.f);

  for (int w0 = 0; w0 < deg; w0 += 64) {
    const int wcnt = min(64, deg - w0);  // wave-uniform
    // ---- Pass A: stage exp for the whole window (independent iterations) ----
#pragma unroll
    for (int t = 0; t < 8; ++t) {
      const int e = t * 8 + j;
      float ex = 0.f;
      int sj = 0;
      if (e < wcnt) {
        sj = col[start + w0 + e];
        float v = a_s[(size_t)sj * 8 + h] + adh;
        v = (v > 0.f) ? v : 0.2f * v;
        ex = __expf(v);
      }
      s_ex[wid][e][h] = ex;
      if (h == 0) s_cols[wid][e] = sj;
      dpart += ex;
    }
    __builtin_amdgcn_wave_barrier();
    // ---- Pass B: feature gathers + FMA, no fences within the window ----
    int e0 = 0;
    for (; e0 + 8 <= wcnt; e0 += 8) {
      int se[8];
      float4 fv[8];
#pragma unroll
      for (int e = 0; e < 8; ++e) se[e] = s_cols[wid][e0 + e];
#pragma unroll
      for (int e = 0; e < 8; ++e)
        fv[e] = *reinterpret_cast<const float4*>(feat + (size_t)se[e] * F + f4 * 4);
#pragma unroll
      for (int e = 0; e < 8; ++e) {
        float alv[HPW];
        if constexpr (HPW == 4)
          *reinterpret_cast<float4*>(alv) =
              *reinterpret_cast<const float4*>(&s_ex[wid][e0 + e][hbase]);
        else
          *reinterpret_cast<float2*>(alv) =
              *reinterpret_cast<const float2*>(&s_ex[wid][e0 + e][hbase]);
#pragma unroll
        for (int q = 0; q < HPW; ++q) {
          acc[q].x = fmaf(alv[q], fv[e].x, acc[q].x);
          acc[q].y = fmaf(alv[q], fv[e].y, acc[q].y);
          acc[q].z = fmaf(alv[q], fv[e].z, acc[q].z);
          acc[q].w = fmaf(alv[q], fv[e].w, acc[q].w);
        }
      }
    }
    for (; e0 < wcnt; ++e0) {  // wave-uniform tail
      int s = s_cols[wid][e0];
      float4 fv = *reinterpret_cast<const float4*>(feat + (size_t)s * F + f4 * 4);
      float alv[HPW];
      if constexpr (HPW == 4)
        *reinterpret_cast<float4*>(alv) =
            *reinterpret_cast<const float4*>(&s_ex[wid][e0][hbase]);
      else
        *reinterpret_cast<float2*>(alv) =
            *reinterpret_cast<const float2*>(&s_ex[wid][e0][hbase]);
#pragma unroll
      for (int q = 0; q < HPW; ++q) {
        acc[q].x = fmaf(alv[q], fv.x, acc[q].x);
        acc[q].y = fmaf(alv[q], fv.y, acc[q].y);
        acc[q].z = fmaf(alv[q], fv.z, acc[q].z);
        acc[q].w = fmaf(alv[q], fv.w, acc[q].w);
      }
    }
    __builtin_amdgcn_wave_barrier();
  }
  // denominator: reduce over edge-slots j (lane bits 3..5) -> every lane
  // holds den for head (lane&7); lanes 0..7 hold den for heads 0..7.
  dpart += __shfl_xor(dpart, 8);
  dpart += __shfl_xor(dpart, 16);
  dpart += __shfl_xor(dpart, 32);
  // deferred normalization + hi/lo split store. __shfl executed by ALL lanes.
#pragma unroll
  for (int q = 0; q < HPW; ++q) {
    float dq = __shfl(dpart, hbase + q);
    float dinv = 1.f / (dq + 1e-16f);
    size_t off = (size_t)node * 8 * F + (size_t)(hbase + q) * F + f4 * 4;
    float4 o = make_float4(acc[q].x * dinv, acc[q].y * dinv,
                           acc[q].z * dinv, acc[q].w * dinv);
    store4split(aggH + off, aggL + off, o);
  }
}

// ==================== fused LSTM activation + attcoef2 ====================

__global__ __launch_bounds__(256) void lstm_act_attcoef_kernel(
    const float* __restrict__ gates, const float* __restrict__ bsum,
    const float* __restrict__ watt2, float* __restrict__ h2,
    float* __restrict__ a_s2, float* __restrict__ a_d2, int n) {
  __shared__ float h2t[4][64];
  __shared__ float wbuf[64 * 16];
  const int tid = threadIdx.x;
  reinterpret_cast<float4*>(wbuf)[tid] = reinterpret_cast<const float4*>(watt2)[tid];
  const int nl = tid >> 6, j = tid & 63;
  const int node = blockIdx.x * 4 + nl;
  float hv = 0.f;
  if (node < n) {
    const float* g0 = gates + (size_t)node * 192;
    float iv = g0[j] + bsum[j];
    float gv = g0[64 + j] + bsum[64 + j];
    float ov = g0[128 + j] + bsum[128 + j];
    float c = (1.f / (1.f + __expf(-iv))) * tanhf(gv);
    hv = fmaxf((1.f / (1.f + __expf(-ov))) * tanhf(c), 0.f);
    h2[(size_t)node * 64 + j] = hv;
  }
  h2t[nl][j] = hv;
  __syncthreads();
  if (j < 16 && node < n) {
    float s = 0.f;
#pragma unroll 16
    for (int f = 0; f < 64; ++f) s = fmaf(h2t[nl][f], wbuf[f * 16 + j], s);
    if (j < 8) a_s2[(size_t)node * 8 + j] = s;
    else       a_d2[(size_t)node * 8 + (j - 8)] = s;
  }
}

// ==================== final row softmax: one WAVE per node ====================

__global__ __launch_bounds__(256) void softmax512_wave(const float* __restrict__ in,
                                                       float* __restrict__ out, int n) {
  const int wid = threadIdx.x >> 6, lane = threadIdx.x & 63;
  const int node = blockIdx.x * 4 + wid;
  if (node >= n) return;
  const float4* ip = reinterpret_cast<const float4*>(in + (size_t)node * 512);
  float4 v0 = ip[lane];
  float4 v1 = ip[64 + lane];
  float m = fmaxf(fmaxf(fmaxf(v0.x, v0.y), fmaxf(v0.z, v0.w)),
                  fmaxf(fmaxf(v1.x, v1.y), fmaxf(v1.z, v1.w)));
#pragma unroll
  for (int d = 1; d < 64; d <<= 1) m = fmaxf(m, __shfl_xor(m, d));
  float4 e0, e1;
  e0.x = __expf(v0.x - m); e0.y = __expf(v0.y - m);
  e0.z = __expf(v0.z - m); e0.w = __expf(v0.w - m);
  e1.x = __expf(v1.x - m); e1.y = __expf(v1.y - m);
  e1.z = __expf(v1.z - m); e1.w = __expf(v1.w - m);
  float s = e0.x + e0.y + e0.z + e0.w + e1.x + e1.y + e1.z + e1.w;
#pragma unroll
  for (int d = 1; d < 64; d <<= 1) s += __shfl_xor(s, d);
  float inv = 1.f / s;
  e0.x *= inv; e0.y *= inv; e0.z *= inv; e0.w *= inv;
  e1.x *= inv; e1.y *= inv; e1.z *= inv; e1.w *= inv;
  float4* op = reinterpret_cast<float4*>(out + (size_t)node * 512);
  op[lane] = e0;
  op[64 + lane] = e1;
}

// ============================ launch ============================

extern "C" void kernel_launch(void* const* d_in, const int* in_sizes, int n_in,
                              void* d_out, int out_size, void* d_ws, size_t ws_size,
                              hipStream_t stream) {
  const float* x      = (const float*)d_in[0];
  const int*   ei     = (const int*)d_in[1];
  const float* W1     = (const float*)d_in[3];
  const float* att_s1 = (const float*)d_in[4];
  const float* att_d1 = (const float*)d_in[5];
  const float* bias1  = (const float*)d_in[6];
  const float* W_ih   = (const float*)d_in[7];
  const float* b_ih   = (const float*)d_in[9];
  const float* b_hh   = (const float*)d_in[10];
  const float* W2     = (const float*)d_in[11];
  const float* att_s2 = (const float*)d_in[12];
  const float* att_d2 = (const float*)d_in[13];
  const float* bias2  = (const float*)d_in[14];
  float* out = (float*)d_out;

  const int N = in_sizes[0] / 128;
  const int E = in_sizes[1] / 2;
  const int* src = ei;
  const int* dst = ei + E;

  char* p = (char*)d_ws;
  auto alloc = [&](size_t bytes) {
    char* r = p;
    p += (bytes + 255) & ~(size_t)255;
    return r;
  };
  char* slotA = alloc((size_t)N * 4096);  // agg1 planes; later gates2+h2+agg2 planes
  char* slotB = alloc((size_t)N * 2048);  // g1 planes; later h3p
  float* a_s1 = (float*)alloc((size_t)N * 8 * 4);
  float* a_d1 = (float*)alloc((size_t)N * 8 * 4);
  float* a_s2 = (float*)alloc((size_t)N * 8 * 4);
  float* a_d2 = (float*)alloc((size_t)N * 8 * 4);
  float* watt1 = (float*)alloc(128 * 16 * 4);
  float* watt2 = (float*)alloc(64 * 16 * 4);
  uint16_t* Wtbh = (uint16_t*)alloc((size_t)192 * 512 * 2);
  uint16_t* Wtbl = (uint16_t*)alloc((size_t)192 * 512 * 2);
  uint16_t* Bt1h = (uint16_t*)alloc((size_t)512 * 128 * 2);
  uint16_t* Bt1l = (uint16_t*)alloc((size_t)512 * 128 * 2);
  uint16_t* Bt2h = (uint16_t*)alloc((size_t)512 * 64 * 2);
  uint16_t* Bt2l = (uint16_t*)alloc((size_t)512 * 64 * 2);
  float* bsum = (float*)alloc(192 * 4);
  int* deg    = (int*)alloc((size_t)2 * N * 4);  // deg + wp adjacent
  int* wp     = deg + N;
  int* rowptr = (int*)alloc((size_t)(N + 1) * 4);
  int* col    = (int*)alloc((size_t)(E + N) * 4);

  // slotA phase 1: agg1 hi/lo planes [N,1024] bf16 each
  uint16_t* agg1h = (uint16_t*)slotA;
  uint16_t* agg1l = agg1h + (size_t)N * 1024;
  // slotA phase 2 (agg1 dead after proj1): gates2 [N,192] f32, h2 [N,64] f32,
  // agg2 hi/lo planes [N,512] bf16 each  (768 + 256 + 1024 + 1024 <= 4096 B/node)
  float* gates2 = (float*)slotA;
  float* h2 = (float*)(slotA + (size_t)N * 768);
  uint16_t* agg2h = (uint16_t*)(slotA + (size_t)N * 1024);
  uint16_t* agg2l = agg2h + (size_t)N * 512;
  // slotB phase 1: g1 hi/lo planes [N,512] bf16 each; phase 2: h3p [N,512] f32
  uint16_t* g1h = (uint16_t*)slotB;
  uint16_t* g1l = g1h + (size_t)N * 512;
  float* h3p = (float*)slotB;

  // ---- merged prep (also zeroes deg/wp) ----
  {
    int total = 2 * N + 98304 + 65536 + 32768 + 192 + 2048 + 1024;
    prep_all_kernel<<<(total + 255) / 256, 256, 0, stream>>>(
        W_ih, b_ih, b_hh, W1, att_s1, att_d1, W2, att_s2, att_d2,
        deg, Wtbh, Wtbl, Bt1h, Bt1l, Bt2h, Bt2l, bsum, watt1, watt2, 2 * N);
  }

  // ---- CSR build ----
  count_kernel<<<(E + 255) / 256, 256, 0, stream>>>(dst, deg, E);
  scan_kernel<<<1, 1024, 0, stream>>>(deg, rowptr, N);
  scatter_kernel<<<(E + N + 255) / 256, 256, 0, stream>>>(src, dst, rowptr, wp, col, E, N);

  const int NYB = (N + 63) / 64;

  // ---- GATConv1: coeffs on x, aggregate x (emit split planes), project ----
  attcoef_kernel<128><<<(N + 15) / 16, 256, 0, stream>>>(x, watt1, a_s1, a_d1, N);
  gat_aggregate_wave<128><<<(N + 3) / 4, 256, 0, stream>>>(x, a_s1, a_d1, rowptr, col,
                                                           agg1h, agg1l, N);
  {
    dim3 g(1, NYB, 8);
    gemm_mfma<true><<<g, 256, 0, stream>>>(
        agg1h, agg1l, Bt1h, Bt1l, nullptr, g1h, g1l, bias1,
        N, 128, /*lda*/1024, /*aZ*/128, /*bZ*/64 * 128, /*ldc*/512, /*cZ*/64, /*biasZ*/64);
  }

  // ---- LSTM gates GEMM + fused act/attcoef2 ----
  {
    dim3 g(3, NYB, 1);
    gemm_mfma<false><<<g, 256, 0, stream>>>(
        g1h, g1l, Wtbh, Wtbl, gates2, nullptr, nullptr, nullptr,
        N, 512, /*lda*/512, 0, 0, /*ldc*/192, 0, 0);
  }
  lstm_act_attcoef_kernel<<<(N + 3) / 4, 256, 0, stream>>>(gates2, bsum, watt2,
                                                           h2, a_s2, a_d2, N);

  // ---- GATConv2: aggregate h2 (emit split planes), project, row softmax ----
  gat_aggregate_wave<64><<<(N + 3) / 4, 256, 0, stream>>>(h2, a_s2, a_d2, rowptr, col,
                                                          agg2h, agg2l, N);
  {
    dim3 g(1, NYB, 8);
    gemm_mfma<false><<<g, 256, 0, stream>>>(
        agg2h, agg2l, Bt2h, Bt2l, h3p, nullptr, nullptr, bias2,
        N, 64, /*lda*/512, /*aZ*/64, /*bZ*/64 * 64, /*ldc*/512, /*cZ*/64, /*biasZ*/64);
  }
  softmax512_wave<<<(N + 3) / 4, 256, 0, stream>>>(h3p, out, N);
}